// Round 6
// baseline (109.499 us; speedup 1.0000x reference)
//
#include <hip/hip_runtime.h>

// Viterbi trellis quantizer: S=1024 states, K=2 (4 preds), CHUNK=4,
// T=64 steps/chain, B=4096 chains (16x16 blocks of a 1024^2 array).
//
// R2-R5 forensics: whenever the per-lane live set exceeds the allocator's
// chosen arch-VGPR tier (32/64), the codebook gets parked in AGPRs and we
// pay ~1 v_accvgpr_read per value per step (~2x inst bloat; R5: 135
// inst/step vs 67 in source at VGPR_Count=32). Fix: FOUR waves per chain,
// one state-group q = tid per thread -> 4 codebook rows = 20 regs, total
// live ~45 -> fits flat. Packed fp32 (v_pk_fma/max via ext_vector_type(2))
// halves the arithmetic instruction count; per-component IEEE semantics
// identical to the scalar version (absmax 0 preserved).
//
// beta-form recurrence (grouped-max):
//   M_t[q] = max_j ( M_{t-1}[(q>>2)+64j] + cb[q+256j]·x_t + h[q+256j] ),
//   h = -||cb||^2/2;  J[t][q] = argmax_j (2 bits, 4 steps packed per byte).
// Traceback: s_t = p + 256*J[t][p], p = s_{t+1}>>2.

typedef float v2f __attribute__((ext_vector_type(2)));

#define COLS      1024
#define T_STEPS   64
#define REC_SIZE  (1024 * 1024)

__global__ __launch_bounds__(256) void viterbi_q(
    const float* __restrict__ arr,
    const float* __restrict__ cbook,
    float* __restrict__ out)
{
    const int tid   = threadIdx.x;   // owned state-group q = tid (0..255)
    const int wid   = tid >> 6;
    const int lane  = tid & 63;
    const int chain = blockIdx.x;    // 0..4095
    const int rb    = chain >> 6;    // block-row
    const int cbc   = chain & 63;    // block-col

    __shared__ __align__(16) float tile[256];     // x chunks
    __shared__ __align__(16) float Mbuf[2][256];  // ping-pong grouped-max M
    __shared__ unsigned char J[16 * 256];         // 4 steps/byte backpointers
    __shared__ int   st_lds[64];                  // traced-back states
    __shared__ float redv[4];
    __shared__ int   reds[4];

    // ---- stage the 16x16 tile ----
    if (tid < 64) {
        const int r  = tid >> 2;
        const int c4 = (tid & 3) << 2;
        float4 v = *(const float4*)(arr + (rb * 16 + r) * COLS + cbc * 16 + c4);
        *(float4*)&tile[tid << 2] = v;
    }
    Mbuf[0][tid] = 0.f;   // M(-1)=0: iter t=0 yields beta0 = cb·x0 + h exactly

    // ---- this thread's 4 codebook rows s = q + 256j, packed over j-pairs ----
    v2f ax01, ay01, az01, aw01, h01;
    v2f ax23, ay23, az23, aw23, h23;
    {
        float4 r0 = *(const float4*)(cbook + (tid       ) * 4);
        float4 r1 = *(const float4*)(cbook + (tid +  256) * 4);
        float4 r2 = *(const float4*)(cbook + (tid +  512) * 4);
        float4 r3 = *(const float4*)(cbook + (tid +  768) * 4);
        ax01 = (v2f){r0.x, r1.x}; ay01 = (v2f){r0.y, r1.y};
        az01 = (v2f){r0.z, r1.z}; aw01 = (v2f){r0.w, r1.w};
        ax23 = (v2f){r2.x, r3.x}; ay23 = (v2f){r2.y, r3.y};
        az23 = (v2f){r2.z, r3.z}; aw23 = (v2f){r2.w, r3.w};
        h01 = (v2f){ -0.5f*(r0.x*r0.x + r0.y*r0.y + r0.z*r0.z + r0.w*r0.w),
                     -0.5f*(r1.x*r1.x + r1.y*r1.y + r1.z*r1.z + r1.w*r1.w) };
        h23 = (v2f){ -0.5f*(r2.x*r2.x + r2.y*r2.y + r2.z*r2.z + r2.w*r2.w),
                     -0.5f*(r3.x*r3.x + r3.y*r3.y + r3.z*r3.z + r3.w*r3.w) };
    }
    __syncthreads();

    const int bq = tid >> 2;   // predecessor base group
    unsigned nib = 0;

    auto step = [&](int t) {
        const float* __restrict__ Mr = Mbuf[t & 1];
        float* __restrict__       Mw = Mbuf[(t + 1) & 1];
        float4 xt = *(const float4*)&tile[t << 2];   // block-uniform broadcast
        const float m0 = Mr[bq], m1 = Mr[bq + 64],
                    m2 = Mr[bq + 128], m3 = Mr[bq + 192];
        v2f acc01 = h01, acc23 = h23;
        const v2f xx = (v2f){xt.x, xt.x}, yy = (v2f){xt.y, xt.y},
                  zz = (v2f){xt.z, xt.z}, ww = (v2f){xt.w, xt.w};
        acc01 = __builtin_elementwise_fma(ax01, xx, acc01);
        acc23 = __builtin_elementwise_fma(ax23, xx, acc23);
        acc01 = __builtin_elementwise_fma(ay01, yy, acc01);
        acc23 = __builtin_elementwise_fma(ay23, yy, acc23);
        acc01 = __builtin_elementwise_fma(az01, zz, acc01);
        acc23 = __builtin_elementwise_fma(az23, zz, acc23);
        acc01 = __builtin_elementwise_fma(aw01, ww, acc01);
        acc23 = __builtin_elementwise_fma(aw23, ww, acc23);
        const v2f c01 = acc01 + (v2f){m0, m1};
        const v2f c23 = acc23 + (v2f){m2, m3};
        const v2f vm  = __builtin_elementwise_max(c01, c23);
        const float v = fmaxf(vm.x, vm.y);
        // first-max index over j=0..3 (== reference first-min over alpha)
        const int j = (c01.x == v) ? 0
                    : (c01.y == v) ? 1
                    : (c23.x == v) ? 2 : 3;
        Mw[tid] = v;
        nib |= (unsigned)j << ((t & 3) * 2);
        if ((t & 3) == 3) { J[(t >> 2) * 256 + tid] = (unsigned char)nib; nib = 0; }
        __syncthreads();
    };

    #pragma unroll 4
    for (int t = 0; t < 60; ++t) step(t);
    #pragma unroll 1
    for (int t = 60; t < 63; ++t) step(t);
    J[15 * 256 + tid] = (unsigned char)nib;   // bits for t = 60, 61, 62

    // ---- final step t = 63: full argmax over beta_63[0..1023] ----
    {
        const float* __restrict__ Mr = Mbuf[63 & 1];
        float4 xt = *(const float4*)&tile[63 << 2];
        const float m0 = Mr[bq], m1 = Mr[bq + 64],
                    m2 = Mr[bq + 128], m3 = Mr[bq + 192];
        v2f acc01 = h01, acc23 = h23;
        const v2f xx = (v2f){xt.x, xt.x}, yy = (v2f){xt.y, xt.y},
                  zz = (v2f){xt.z, xt.z}, ww = (v2f){xt.w, xt.w};
        acc01 = __builtin_elementwise_fma(ax01, xx, acc01);
        acc23 = __builtin_elementwise_fma(ax23, xx, acc23);
        acc01 = __builtin_elementwise_fma(ay01, yy, acc01);
        acc23 = __builtin_elementwise_fma(ay23, yy, acc23);
        acc01 = __builtin_elementwise_fma(az01, zz, acc01);
        acc23 = __builtin_elementwise_fma(az23, zz, acc23);
        acc01 = __builtin_elementwise_fma(aw01, ww, acc01);
        acc23 = __builtin_elementwise_fma(aw23, ww, acc23);
        const float cv0 = acc01.x + m0, cv1 = acc01.y + m1;
        const float cv2 = acc23.x + m2, cv3 = acc23.y + m3;
        float bv = cv0; int bs = tid;              // state = q + 256*j, asc j
        if (cv1 > bv) { bv = cv1; bs = tid + 256; }
        if (cv2 > bv) { bv = cv2; bs = tid + 512; }
        if (cv3 > bv) { bv = cv3; bs = tid + 768; }
        // lexicographic (value desc, state asc) butterfly within the wave
        #pragma unroll
        for (int off = 32; off > 0; off >>= 1) {
            const float ov = __shfl_xor(bv, off, 64);
            const int   os = __shfl_xor(bs, off, 64);
            if (ov > bv || (ov == bv && os < bs)) { bv = ov; bs = os; }
        }
        if (lane == 0) { redv[wid] = bv; reds[wid] = bs; }
    }
    __syncthreads();   // covers redv/reds and the J tail writes

    // ---- traceback (serial, thread 0) ----
    if (tid == 0) {
        float bv = redv[0]; int bs = reds[0];
        #pragma unroll
        for (int w = 1; w < 4; ++w)
            if (redv[w] > bv || (redv[w] == bv && reds[w] < bs)) {
                bv = redv[w]; bs = reds[w];
            }
        int s = bs;
        st_lds[T_STEPS - 1] = s;
        for (int i = T_STEPS - 2; i >= 0; --i) {
            const int p = s >> 2;
            const unsigned byte = J[(i >> 2) * 256 + p];
            const int j = (byte >> ((i & 3) * 2)) & 3;
            s = p + (j << 8);
            st_lds[i] = s;
        }
    }
    __syncthreads();

    // ---- outputs ----
    if (tid < 64) {
        // rec: step t covers elements 4t..4t+3 -> row t>>2, cols 4*(t&3)..+3
        const int st = st_lds[tid];
        const float4 v = *(const float4*)(cbook + st * 4);
        const int r  = tid >> 2;
        const int c4 = (tid & 3) << 2;
        *(float4*)(out + (rb * 16 + r) * COLS + cbc * 16 + c4) = v;
    } else if (tid < 128) {
        // states flat: REC_SIZE + chain*64 + t (stored as float values)
        const int t = tid - 64;
        out[REC_SIZE + chain * 64 + t] = (float)st_lds[t];
    }
}

extern "C" void kernel_launch(void* const* d_in, const int* in_sizes, int n_in,
                              void* d_out, int out_size, void* d_ws, size_t ws_size,
                              hipStream_t stream)
{
    const float* arr   = (const float*)d_in[0];
    const float* cbook = (const float*)d_in[1];
    float* out = (float*)d_out;
    // one chain per 256-thread block (4 waves/chain), 4096 blocks
    viterbi_q<<<dim3(4096), dim3(256), 0, stream>>>(arr, cbook, out);
}